// Round 10
// baseline (116.941 us; speedup 1.0000x reference)
//
#include <hip/hip_runtime.h>

// CIN fused 3-layer, bf16 MFMA (R16): R15 + lane-linear W-tile layout.
// cur[sl,n] = sum_f x_f[sl] * S_f[sl,n],  S_f = sum_g h_g[sl] * W[f*64+g, n].
//
// R15 post-mortem: register war WON (VGPR 60, zero spill, 57.3 us) but
// SQ_LDS_BANK_CONFLICT 85K -> 2.08M (24x). The wa read had a 64-byte
// c-lane stride (bank ~8-way: c*64 + q*16) on the hottest read (16/f/CU).
// R16 single variable: permute wt so frag (ks, n=wn*16+c, q) sits at
// shorts ks*4096 + wn*512 + (q*16+c)*8 -> wave reads base + lane*8,
// consecutive lanes = consecutive 16B = conflict-free (the DMA-write /
// R8-read pattern). Per-lane frag CONTENT identical to R15 (correctness
// inherited); only prep write index + main bofs change.
//
// Structure (R15, verified passing):
//  - swapped mfma(A=W^T, B=h): h is B-operand -> 4 persistent hb frags
//    (16 regs, own ks-half); W streams LDS->VGPR 1 b128/f/wave.
//  - x as per-lane f32x4 over st via xS[d][f][st] (stride 41, 2-way banks,
//    q-broadcast); 1 b128/f/wave. Zero global loads in the K-loop.
//  - ks-split waves (8n x 2ks); partial cur exchanged once per layer
//    through the DEAD Bbuf half. DMA dbuf staging, PH_T=4, 1 barrier/phase.
//  Peak regs ~52-60 (<= the empirical 64 wall). No spill.
//
// wt layout (prep output), tile tl = l*40+f (f=39 zero tile):
//   frag(ks, q, n): 8 shorts at tl*8192 + ks*4096 + (n>>4)*512 + ((q*16)+(n&15))*8
//   content j=0..7: bf16(W_l[f*64 + ks*32 + q*8 + j][n])

#define NF      39
#define LCH     128
#define NLAYER  3
#define LSTR    40                  // padded tiles per layer
#define NTILES  (NLAYER * LSTR)     // 120
#define TILE_SH 8192                // shorts per tile (16 KB)
#define PH_T    4                   // tiles per phase
#define BUF_SH  (PH_T * TILE_SH)    // 32768 shorts (64 KB)
#define NPH     (LSTR / PH_T)       // 10 phases per layer
#define SLN     64                  // slices per block (4 batches x 16 d)
#define XSL     41                  // xS f-slot stride (bank spread, 2-way)
#define XSTR    (NF * 16)           // 624 floats per batch row

typedef __bf16        bf16x8 __attribute__((ext_vector_type(8)));
typedef unsigned int  uint4v __attribute__((ext_vector_type(4)));
typedef float         f32x4  __attribute__((ext_vector_type(4)));

__device__ __forceinline__ unsigned short f2bf_rne(float f) {
    unsigned u = __float_as_uint(f);
    u += 0x7fffu + ((u >> 16) & 1u);
    return (unsigned short)(u >> 16);
}

// ---------------- prep: W fp32 -> bf16 frag-ready transposed tiles ----------
// thread t -> uint4v index t; decode c/q/wn/ks/tl so the WRITE is linear.
__global__ void cin_prep(const float* __restrict__ W0,
                         const float* __restrict__ W1,
                         const float* __restrict__ W2,
                         unsigned short* __restrict__ wt)
{
    const int t = blockIdx.x * blockDim.x + threadIdx.x;
    if (t >= NTILES * 1024) return;
    const int c  = t & 15;          // n low bits
    const int q  = (t >> 4) & 3;    // quad
    const int wn = (t >> 6) & 7;    // n high bits
    const int ks = (t >> 9) & 1;
    const int tl = t >> 10;
    const int n  = wn * 16 + c;
    const int l  = tl / LSTR;
    const int f  = tl - l * LSTR;
    const float* W = (l == 0) ? W0 : (l == 1) ? W1 : W2;

    unsigned short v[8];
    #pragma unroll
    for (int j = 0; j < 8; ++j) {
        const int g = ks * 32 + q * 8 + j;
        float w = 0.0f;
        if (f < NF) {
            if (l == 0) { if (g < NF) w = W[(f * NF + g) * LCH + n]; }
            else        { w = W[(f * 64 + g) * LCH + n]; }
        }
        v[j] = f2bf_rne(w);
    }
    uint4v pv;
    #pragma unroll
    for (int i = 0; i < 4; ++i)
        pv[i] = (unsigned)v[2 * i] | ((unsigned)v[2 * i + 1] << 16);
    ((uint4v*)wt)[t] = pv;   // 16B, write index linear in t
}

// ---------------- main ----------------
__global__ __launch_bounds__(1024, 4) void cin_mfma(
    const float* __restrict__ x,
    const unsigned short* __restrict__ wt,
    const float* __restrict__ b0p,
    const float* __restrict__ b1p,
    const float* __restrict__ b2p,
    float* __restrict__ out)
{
    __shared__ __align__(16) unsigned short Bbuf[2 * BUF_SH];   // 128 KB W dbuf
    __shared__ __align__(16) unsigned short hfrag[8 * SLN * 8]; // 8 KB
    __shared__ __align__(16) float xS[16 * XSL * 4];            // 10.25 KB [d][f][st]
    __shared__ float biasl[NLAYER * LCH];                       // 1.5 KB

    const int tid  = threadIdx.x;
    const int lane = tid & 63;
    const int w    = tid >> 6;      // wave 0..15
    const int wn   = w & 7;         // n-tile
    const int ksh  = w >> 3;        // ks-half (g in [ksh*32, ksh*32+32))
    const int q    = lane >> 4;     // quad 0..3
    const int c    = lane & 15;
    const int bb   = blockIdx.x * 4;

    // zero hfrag first (covers layer-0 padding g in [39,64))
    if (tid < 512) {
        f32x4 z4 = {0.f, 0.f, 0.f, 0.f};
        ((f32x4*)hfrag)[tid] = z4;
    }
    __syncthreads();   // zero visible before partial hfrag writes

    // stage x: hfrag (layer-0 h, bf16) + xS[d][f][st] (fp32)
    for (int i = tid; i < 4 * XSTR; i += 1024) {
        const float v = x[bb * XSTR + i];
        const int lb = i / XSTR;
        const int r  = i - lb * XSTR;
        const int f  = r >> 4;
        const int d  = r & 15;
        hfrag[((f >> 3) * SLN + lb * 16 + d) * 8 + (f & 7)] = f2bf_rne(v);
        xS[(d * XSL + f) * 4 + lb] = v;
    }
    // zero xS f=39 slot (read at f=39; W tile is zero but NaN*0 would poison)
    if (tid < 64) xS[((tid >> 2) * XSL + NF) * 4 + (tid & 3)] = 0.f;
    if (tid < NLAYER * LCH)
        biasl[tid] = (tid < 128) ? b0p[tid] : (tid < 256) ? b1p[tid-128] : b2p[tid-256];

    // prologue B staging: tiles 0..3 -> buf0 (each wave 1 KB per tile)
    {
        const unsigned short* src = wt + w * 512 + lane * 8;
        unsigned short* dst = Bbuf + w * 512;
        #pragma unroll
        for (int k = 0; k < PH_T; ++k)
            __builtin_amdgcn_global_load_lds((const void*)(src + k * TILE_SH),
                                             (void*)(dst + k * TILE_SH), 16, 0, 0);
    }
    __syncthreads();   // hfrag, xS, bias, buf0 ready

    // per-lane constants: wa read base = wave segment + lane*8 (lane-linear,
    // conflict-free: consecutive lanes -> consecutive 16B)
    const int bofs = ksh * 4096 + wn * 512 + lane * 8;  // shorts within tile
    const int xbl  = c * XSL;                            // xS slot base

    int cb = 0;
    #pragma unroll 1
    for (int l = 0; l < NLAYER; ++l) {
        // hoist h B-frags (own ks-half, 4 st): 16 VGPR persistent
        bf16x8 hb0 = *(const bf16x8*)&hfrag[((ksh * 4 + q) * SLN +  0 + c) * 8];
        bf16x8 hb1 = *(const bf16x8*)&hfrag[((ksh * 4 + q) * SLN + 16 + c) * 8];
        bf16x8 hb2 = *(const bf16x8*)&hfrag[((ksh * 4 + q) * SLN + 32 + c) * 8];
        bf16x8 hb3 = *(const bf16x8*)&hfrag[((ksh * 4 + q) * SLN + 48 + c) * 8];

        const f32x4 zz = {0.f, 0.f, 0.f, 0.f};
        f32x4 cur0 = zz, cur1 = zz, cur2 = zz, cur3 = zz;

        #pragma unroll 1
        for (int p = 0; p < NPH; ++p) {
            // stage next phase (issue-early / drain at the phase barrier)
            const int nbt = l * LSTR + p * PH_T + PH_T;
            if (nbt < NTILES) {
                const unsigned short* src = wt + (size_t)nbt * TILE_SH + w * 512 + lane * 8;
                unsigned short* dst = &Bbuf[(cb ^ 1) * BUF_SH + w * 512];
                #pragma unroll
                for (int k = 0; k < PH_T; ++k)
                    __builtin_amdgcn_global_load_lds((const void*)(src + k * TILE_SH),
                                                     (void*)(dst + k * TILE_SH), 16, 0, 0);
            }
            const unsigned short* tb = Bbuf + cb * BUF_SH + bofs;
            const int p4 = p * PH_T;

            // per f: 1 wa b128 (lane-linear, shared by 4 MFMAs) + 1 xr b128.
            #define F_ITER(K)                                                       \
            {                                                                       \
                const f32x4 xr = *(const f32x4*)&xS[(xbl + p4 + (K)) * 4];          \
                const bf16x8 wa = *(const bf16x8*)(tb + (K) * TILE_SH);             \
                f32x4 sv;                                                           \
                sv = __builtin_amdgcn_mfma_f32_16x16x32_bf16(wa, hb0, zz, 0, 0, 0); \
                _Pragma("unroll")                                                   \
                for (int r = 0; r < 4; ++r) cur0[r] = fmaf(xr[0], sv[r], cur0[r]);  \
                sv = __builtin_amdgcn_mfma_f32_16x16x32_bf16(wa, hb1, zz, 0, 0, 0); \
                _Pragma("unroll")                                                   \
                for (int r = 0; r < 4; ++r) cur1[r] = fmaf(xr[1], sv[r], cur1[r]);  \
                sv = __builtin_amdgcn_mfma_f32_16x16x32_bf16(wa, hb2, zz, 0, 0, 0); \
                _Pragma("unroll")                                                   \
                for (int r = 0; r < 4; ++r) cur2[r] = fmaf(xr[2], sv[r], cur2[r]);  \
                sv = __builtin_amdgcn_mfma_f32_16x16x32_bf16(wa, hb3, zz, 0, 0, 0); \
                _Pragma("unroll")                                                   \
                for (int r = 0; r < 4; ++r) cur3[r] = fmaf(xr[3], sv[r], cur3[r]);  \
            }
            F_ITER(0) F_ITER(1) F_ITER(2) F_ITER(3)
            #undef F_ITER

            __syncthreads();   // drain staging + buffer handoff
            cb ^= 1;
        }

        // ------- layer end: ks-reduce through the DEAD Bbuf half -------
        // after the last flip, Bbuf[cb^1] is the just-consumed buffer (dead);
        // Bbuf[cb] holds next layer's phase-0 tiles (staged during p=9).
        float* exch = (float*)(Bbuf + (cb ^ 1) * BUF_SH);   // 32 KB of 64 used
        if (ksh == 1) {
            // component-sliced: consecutive lanes -> consecutive dwords
            #define RW(ST, CURV)                                                    \
            _Pragma("unroll")                                                       \
            for (int r = 0; r < 4; ++r)                                             \
                exch[((ST) * 4 + r) * 512 + wn * 64 + lane] = CURV[r];
            RW(0, cur0) RW(1, cur1) RW(2, cur2) RW(3, cur3)
            #undef RW
        }
        __syncthreads();
        if (ksh == 0) {
            const f32x4 bq = *(const f32x4*)&biasl[l * LCH + wn * 16 + q * 4];
            float v0[4], v1[4], v2[4], v3[4];
            #define RD(ST, CURV, VV)                                                \
            _Pragma("unroll")                                                       \
            for (int r = 0; r < 4; ++r)                                             \
                VV[r] = fmaxf(CURV[r] +                                             \
                              exch[((ST) * 4 + r) * 512 + wn * 64 + lane] +         \
                              bq[r], 0.f);
            RD(0, cur0, v0) RD(1, cur1, v1) RD(2, cur2, v2) RD(3, cur3, v3)
            #undef RD

            if (l < 2 && wn < 4) {
                // h channels (n<64): write next layer's h; n = wn*16+q*4+r,
                // sl = st*16+c
                #define HWR(ST, VV)                                                 \
                _Pragma("unroll")                                                   \
                for (int r = 0; r < 4; ++r) {                                       \
                    const int n = wn * 16 + q * 4 + r;                              \
                    hfrag[((n >> 3) * SLN + (ST) * 16 + c) * 8 + (n & 7)] =         \
                        f2bf_rne(VV[r]);                                            \
                }
                HWR(0, v0) HWR(1, v1) HWR(2, v2) HWR(3, v3)
                #undef HWR
            } else {
                // direct: reduce over d (= c lanes) and store
                // l==0: n 64..127 -> out 0..63; l==1: n -> 64..127; l==2: 128+n
                #define DST(ST, VV)                                                 \
                _Pragma("unroll")                                                   \
                for (int r = 0; r < 4; ++r) {                                       \
                    float s = VV[r];                                                \
                    s += __shfl_xor(s, 1, 64);                                      \
                    s += __shfl_xor(s, 2, 64);                                      \
                    s += __shfl_xor(s, 4, 64);                                      \
                    s += __shfl_xor(s, 8, 64);                                      \
                    if (c == 0) {                                                   \
                        const int n = wn * 16 + q * 4 + r;                          \
                        const int outcol = (l == 0) ? n - 64                        \
                                         : (l == 1) ? n : 128 + n;                  \
                        out[(bb + (ST)) * 256 + outcol] = s;                        \
                    }                                                               \
                }
                DST(0, v0) DST(1, v1) DST(2, v2) DST(3, v3)
                #undef DST
            }
        }
        if (l < 2) __syncthreads();   // h writes visible before next hb hoist
    }
}

extern "C" void kernel_launch(void* const* d_in, const int* in_sizes, int n_in,
                              void* d_out, int out_size, void* d_ws, size_t ws_size,
                              hipStream_t stream) {
    const float* x  = (const float*)d_in[0];
    const float* W0 = (const float*)d_in[1];
    const float* W1 = (const float*)d_in[2];
    const float* W2 = (const float*)d_in[3];
    const float* b0 = (const float*)d_in[4];
    const float* b1 = (const float*)d_in[5];
    const float* b2 = (const float*)d_in[6];
    float* out = (float*)d_out;
    unsigned short* wt = (unsigned short*)d_ws;  // 120*8192*2 B = 1.97 MB

    const int prep_threads = NTILES * 1024;      // 122880
    cin_prep<<<(prep_threads + 255) / 256, 256, 0, stream>>>(W0, W1, W2, wt);
    cin_mfma<<<256, 1024, 0, stream>>>(x, wt, b0, b1, b2, out);
}